// Round 7
// baseline (420.766 us; speedup 1.0000x reference)
//
#include <hip/hip_runtime.h>
#include <climits>

#define IN_F 4096
#define OUT_F 4096
#define BATCH 4096
#define NPART 1024   // partial-reduction slots for weight min/max

typedef __bf16 bf16x8 __attribute__((ext_vector_type(8)));
typedef float f32x4 __attribute__((ext_vector_type(4)));
typedef unsigned short u16x8 __attribute__((ext_vector_type(8)));

__device__ __forceinline__ unsigned short f2bf_rne(float f) {
  unsigned int u = __float_as_uint(f);
  u += 0x7fffu + ((u >> 16) & 1u);
  return (unsigned short)(u >> 16);
}

__device__ __forceinline__ u16x8 cvt8f(float4 a, float4 b) {
  u16x8 h;
  h[0] = f2bf_rne(a.x); h[1] = f2bf_rne(a.y); h[2] = f2bf_rne(a.z); h[3] = f2bf_rne(a.w);
  h[4] = f2bf_rne(b.x); h[5] = f2bf_rne(b.y); h[6] = f2bf_rne(b.z); h[7] = f2bf_rne(b.w);
  return h;
}
__device__ __forceinline__ u16x8 cvt8i(int4 a, int4 b) {
  u16x8 h;
  h[0] = f2bf_rne((float)a.x); h[1] = f2bf_rne((float)a.y);
  h[2] = f2bf_rne((float)a.z); h[3] = f2bf_rne((float)a.w);
  h[4] = f2bf_rne((float)b.x); h[5] = f2bf_rne((float)b.y);
  h[6] = f2bf_rne((float)b.z); h[7] = f2bf_rne((float)b.w);
  return h;
}

// ---------------- weight min/max partials (needed pre-GEMM: global reduction) ----------------
__global__ __launch_bounds__(256) void k_wmm(const int* __restrict__ q,
                                             int* __restrict__ pmin,
                                             int* __restrict__ pmax) {
  const int n4 = (OUT_F * IN_F) / 4;
  const int stride = gridDim.x * blockDim.x;
  int vmin = INT_MAX, vmax = INT_MIN;
  const int4* q4 = (const int4*)q;
  for (int i = blockIdx.x * blockDim.x + threadIdx.x; i < n4; i += stride) {
    int4 v = q4[i];
    vmin = min(vmin, min(min(v.x, v.y), min(v.z, v.w)));
    vmax = max(vmax, max(max(v.x, v.y), max(v.z, v.w)));
  }
  for (int off = 32; off > 0; off >>= 1) {
    vmin = min(vmin, __shfl_down(vmin, off));
    vmax = max(vmax, __shfl_down(vmax, off));
  }
  __shared__ int rmin[4], rmax[4];
  const int wave = threadIdx.x >> 6;
  if ((threadIdx.x & 63) == 0) { rmin[wave] = vmin; rmax[wave] = vmax; }
  __syncthreads();
  if (threadIdx.x == 0) {
    pmin[blockIdx.x] = min(min(rmin[0], rmin[1]), min(rmin[2], rmin[3]));
    pmax[blockIdx.x] = max(max(rmax[0], rmax[1]), max(rmax[2], rmax[3]));
  }
}

// ---------------- reduce partials + bias min/max, compute affine scalars (fallback) ----------------
__global__ __launch_bounds__(256) void k_scal(const int* __restrict__ pmin,
                                              const int* __restrict__ pmax, int npart,
                                              const int* __restrict__ bq,
                                              const float* __restrict__ wmn,
                                              const float* __restrict__ wmx,
                                              const float* __restrict__ bmn,
                                              const float* __restrict__ bmx,
                                              float* __restrict__ scal) {
  int vmin = INT_MAX, vmax = INT_MIN;
  for (int i = threadIdx.x; i < npart; i += 256) {
    vmin = min(vmin, pmin[i]);
    vmax = max(vmax, pmax[i]);
  }
  int bmin = INT_MAX, bmaxv = INT_MIN;
  for (int i = threadIdx.x; i < OUT_F; i += 256) {
    int v = bq[i];
    bmin = min(bmin, v);
    bmaxv = max(bmaxv, v);
  }
  for (int off = 32; off > 0; off >>= 1) {
    vmin = min(vmin, __shfl_down(vmin, off));
    vmax = max(vmax, __shfl_down(vmax, off));
    bmin = min(bmin, __shfl_down(bmin, off));
    bmaxv = max(bmaxv, __shfl_down(bmaxv, off));
  }
  __shared__ int r[4][4];
  const int wave = threadIdx.x >> 6;
  if ((threadIdx.x & 63) == 0) {
    r[wave][0] = vmin; r[wave][1] = vmax; r[wave][2] = bmin; r[wave][3] = bmaxv;
  }
  __syncthreads();
  if (threadIdx.x == 0) {
    int qmin = min(min(r[0][0], r[1][0]), min(r[2][0], r[3][0]));
    int qmax = max(max(r[0][1], r[1][1]), max(r[2][1], r[3][1]));
    int qbmin = min(min(r[0][2], r[1][2]), min(r[2][2], r[3][2]));
    int qbmax = max(max(r[0][3], r[1][3]), max(r[2][3], r[3][3]));
    float ws = (*wmx - *wmn) / (float)(qmax - qmin);
    scal[0] = ws;
    scal[1] = *wmn - ws * (float)qmin;
    float bs = (*bmx - *bmn) / (float)(qbmax - qbmin);
    scal[2] = bs;
    scal[3] = *bmn - bs * (float)qbmin;
  }
}

// ---------------- R10: FULLY FUSED 256x256 bf16 MFMA GEMM ----------------
// Reads x (fp32) and wq (int32) directly; converts to bf16 during reg-staged LDS
// staging (T14 path — forced: staging must change dtype). Eliminates k_convW/k_convX
// and the 100 MB xb/qb workspace round-trip. Rationale: non-GEMM residual was
// 168-176 us across SIX conversion-kernel variants (merged/split, 8B/16B stores) —
// invariant to internals, so remove the kernels/launches/traffic entirely.
// rowsum folds into staging free: each staging lane covers fixed rows rowS0/rowS0+16,
// accumulates fp32 sums, 4-lane shuffle reduce -> LDS -> epilogue.
//
// Schedule per K32-iter t (2-slot LDS dbuf, depth-1 prefetch):
//   issue 8 global loads (tile t+1: A fp32 32B + B int32 32B per lane) -> regs
//   CFENCE (pin issue early)                    [loads fly under everything below]
//   ds_read fa/fb (8x b128, slot t&1) -> MFMA cluster0 (16)
//   ds_read fa2 (4x) -> MFMA cluster1 (16)      [compiler inserts counted lgkm]
//   convert regs -> 4x ds_write_b128 (slot d); accumulate rowsum partials
//   __syncthreads()                              [full drain = exactly the semantics needed]
// Race-freedom: reads of slot s happen at top of t; writes to s happen in t+1, after
// the t-end barrier -> separated. Load->use window ~2000+ cyc >> 900-cyc HBM miss;
// x (67 MB) and wq (67 MB) both L3-resident so re-reads are cache hits.
#define CFENCE asm volatile("" ::: "memory")

__global__ __launch_bounds__(512, 2) void k_gemm(
    const float* __restrict__ X,      // x  fp32 [BATCH][IN_F]
    const int* __restrict__ WQ,       // q  int32 [OUT_F][IN_F]
    const int* __restrict__ bq,
    const int* __restrict__ pmin,
    const int* __restrict__ pmax,
    const float* __restrict__ wmn, const float* __restrict__ wmx,
    const float* __restrict__ bmn, const float* __restrict__ bmx,
    float* __restrict__ C) {
  __shared__ __align__(16) unsigned short As[2][8192];   // 2 slots x 256 rows x 32 cols
  __shared__ __align__(16) unsigned short Bs[2][8192];
  __shared__ float rowsumS[256];
  __shared__ int rr[8][4];
  __shared__ float s_scal[4];

  const int tid = threadIdx.x;
  const int w = tid >> 6;
  const int lane = tid & 63;
  const int bm = blockIdx.x * 256;
  const int bn = blockIdx.y * 256;

  // ---- folded scal: block-redundant affine-scalar reduction (drained by syncthreads) ----
  {
    int vmin = INT_MAX, vmax = INT_MIN;
    for (int i = tid; i < NPART; i += 512) {
      vmin = min(vmin, pmin[i]);
      vmax = max(vmax, pmax[i]);
    }
    int bmn_ = INT_MAX, bmx_ = INT_MIN;
    for (int i = tid; i < OUT_F; i += 512) {
      int v = bq[i];
      bmn_ = min(bmn_, v);
      bmx_ = max(bmx_, v);
    }
    for (int off = 32; off > 0; off >>= 1) {
      vmin = min(vmin, __shfl_down(vmin, off));
      vmax = max(vmax, __shfl_down(vmax, off));
      bmn_ = min(bmn_, __shfl_down(bmn_, off));
      bmx_ = max(bmx_, __shfl_down(bmx_, off));
    }
    if ((tid & 63) == 0) { rr[w][0] = vmin; rr[w][1] = vmax; rr[w][2] = bmn_; rr[w][3] = bmx_; }
    __syncthreads();
    if (tid == 0) {
      int qmin = rr[0][0], qmax = rr[0][1], qbmin = rr[0][2], qbmax = rr[0][3];
      for (int i = 1; i < 8; ++i) {
        qmin = min(qmin, rr[i][0]); qmax = max(qmax, rr[i][1]);
        qbmin = min(qbmin, rr[i][2]); qbmax = max(qbmax, rr[i][3]);
      }
      float ws = (*wmx - *wmn) / (float)(qmax - qmin);
      s_scal[0] = ws;
      s_scal[1] = *wmn - ws * (float)qmin;
      float bs = (*bmx - *bmn) / (float)(qbmax - qbmin);
      s_scal[2] = bs;
      s_scal[3] = *bmn - bs * (float)qbmin;
    }
  }

  const int wm = (w & 1) * 128;    // wave's 128x64 output subtile
  const int wn = (w >> 1) * 64;
  const int r16 = lane & 15;
  const int q = lane >> 4;
  const int pc = (q ^ ((r16 >> 1) & 3)) * 8;   // swizzled fragment-read chunk

  // staging coords: lane covers chunks cA0 (row rowS0) and cA0+64 (row rowS0+16).
  // LDS layout: phys chunk p of row r holds global k-chunk p^((r>>1)&3) (pre-swizzle
  // applied on the GLOBAL column; LDS write address is linear in chunk index).
  const int cA0 = w * 128 + lane;
  const int rowS0 = cA0 >> 2;                               // 0..255
  const int colS0 = ((cA0 & 3) ^ ((rowS0 >> 1) & 3)) * 8;   // element offset in K-tile
  const int rowS1 = rowS0 + 16;
  const int colS1 = ((cA0 & 3) ^ ((rowS1 >> 1) & 3)) * 8;
  const float* xs0 = X + (size_t)(bm + rowS0) * IN_F + colS0;
  const float* xs1 = X + (size_t)(bm + rowS1) * IN_F + colS1;
  const int* ws0 = WQ + (size_t)(bn + rowS0) * IN_F + colS0;
  const int* ws1 = WQ + (size_t)(bn + rowS1) * IN_F + colS1;
  const int dstu0 = w * 1024 + lane * 8;        // ushort offset of lane's 16B chunk, load 0
  const int dstu1 = dstu0 + 512;                // load 1

  f32x4 acc[8][4] = {};
  float rsum0 = 0.f, rsum1 = 0.f;

  const int NT = IN_F / 32;   // 128 K-subtiles

  // ---- prologue: stage tile 0 into slot 0 ----
  {
    float4 a0a = *(const float4*)(xs0);
    float4 a0b = *(const float4*)(xs0 + 4);
    float4 a1a = *(const float4*)(xs1);
    float4 a1b = *(const float4*)(xs1 + 4);
    int4 b0a = *(const int4*)(ws0);
    int4 b0b = *(const int4*)(ws0 + 4);
    int4 b1a = *(const int4*)(ws1);
    int4 b1b = *(const int4*)(ws1 + 4);
    rsum0 += ((a0a.x + a0a.y) + (a0a.z + a0a.w)) + ((a0b.x + a0b.y) + (a0b.z + a0b.w));
    rsum1 += ((a1a.x + a1a.y) + (a1a.z + a1a.w)) + ((a1b.x + a1b.y) + (a1b.z + a1b.w));
    *(u16x8*)&As[0][dstu0] = cvt8f(a0a, a0b);
    *(u16x8*)&As[0][dstu1] = cvt8f(a1a, a1b);
    *(u16x8*)&Bs[0][dstu0] = cvt8i(b0a, b0b);
    *(u16x8*)&Bs[0][dstu1] = cvt8i(b1a, b1b);
  }
  __syncthreads();

  for (int t = 0; t < NT; ++t) {
    const int s = t & 1;
    const int d = s ^ 1;
    const unsigned short* Asl = As[s];
    const unsigned short* Bsl = Bs[s];
    const int koff = (t + 1) * 32;
    const bool pf = (t + 1 < NT);

    // ---- issue next tile's global loads (pinned early; fly under MFMA) ----
    float4 a0a, a0b, a1a, a1b;
    int4 b0a, b0b, b1a, b1b;
    if (pf) {
      a0a = *(const float4*)(xs0 + koff);
      a0b = *(const float4*)(xs0 + koff + 4);
      a1a = *(const float4*)(xs1 + koff);
      a1b = *(const float4*)(xs1 + koff + 4);
      b0a = *(const int4*)(ws0 + koff);
      b0b = *(const int4*)(ws0 + koff + 4);
      b1a = *(const int4*)(ws1 + koff);
      b1b = *(const int4*)(ws1 + koff + 4);
    }
    CFENCE;

    // ---- compute on slot s ----
    bf16x8 fa[4], fb[4];
#pragma unroll
    for (int i = 0; i < 4; ++i)
      fa[i] = *(const bf16x8*)&Asl[(wm + i * 16 + r16) * 32 + pc];
#pragma unroll
    for (int i = 0; i < 4; ++i)
      fb[i] = *(const bf16x8*)&Bsl[(wn + i * 16 + r16) * 32 + pc];
    __builtin_amdgcn_s_setprio(1);
#pragma unroll
    for (int mi = 0; mi < 4; ++mi)
#pragma unroll
      for (int ni = 0; ni < 4; ++ni)
        acc[mi][ni] = __builtin_amdgcn_mfma_f32_16x16x32_bf16(fa[mi], fb[ni], acc[mi][ni], 0, 0, 0);
    __builtin_amdgcn_s_setprio(0);
    bf16x8 fa2[4];
#pragma unroll
    for (int i = 0; i < 4; ++i)
      fa2[i] = *(const bf16x8*)&Asl[(wm + 64 + i * 16 + r16) * 32 + pc];
    __builtin_amdgcn_s_setprio(1);
#pragma unroll
    for (int mi = 0; mi < 4; ++mi)
#pragma unroll
      for (int ni = 0; ni < 4; ++ni)
        acc[4 + mi][ni] = __builtin_amdgcn_mfma_f32_16x16x32_bf16(fa2[mi], fb[ni], acc[4 + mi][ni], 0, 0, 0);
    __builtin_amdgcn_s_setprio(0);

    // ---- convert + write next tile into slot d; accumulate rowsum ----
    if (pf) {
      rsum0 += ((a0a.x + a0a.y) + (a0a.z + a0a.w)) + ((a0b.x + a0b.y) + (a0b.z + a0b.w));
      rsum1 += ((a1a.x + a1a.y) + (a1a.z + a1a.w)) + ((a1b.x + a1b.y) + (a1b.z + a1b.w));
      *(u16x8*)&As[d][dstu0] = cvt8f(a0a, a0b);
      *(u16x8*)&As[d][dstu1] = cvt8f(a1a, a1b);
      *(u16x8*)&Bs[d][dstu0] = cvt8i(b0a, b0b);
      *(u16x8*)&Bs[d][dstu1] = cvt8i(b1a, b1b);
    }
    __syncthreads();   // publishes slot d; drains all reads of slot s
  }

  // ---- rowsum: 4-lane reduce (lanes 4j..4j+3 share rows rowS0/rowS1) -> LDS ----
  rsum0 += __shfl_down(rsum0, 2);
  rsum0 += __shfl_down(rsum0, 1);
  rsum1 += __shfl_down(rsum1, 2);
  rsum1 += __shfl_down(rsum1, 1);
  if ((lane & 3) == 0) {
    rowsumS[rowS0] = rsum0;
    rowsumS[rowS1] = rsum1;
  }
  __syncthreads();

  // ---- epilogue ----
  const float wsc = s_scal[0], wbe = s_scal[1], bsc = s_scal[2], bbe = s_scal[3];
#pragma unroll
  for (int ni = 0; ni < 4; ++ni) {
    const int gn = bn + wn + ni * 16 + r16;            // C/D: col = lane&15
    const float bdq = bsc * (float)bq[gn] + bbe;
#pragma unroll
    for (int mi = 0; mi < 8; ++mi) {
      const int lm0 = wm + mi * 16 + q * 4;            // C/D: row = quad*4 + reg
#pragma unroll
      for (int r = 0; r < 4; ++r) {
        const int lm = lm0 + r;
        C[(size_t)(bm + lm) * OUT_F + gn] = wsc * acc[mi][ni][r] + wbe * rowsumS[lm] + bdq;
      }
    }
  }
}

// ---------------- fallback (workspace too small): dequant-on-the-fly naive GEMM ----------------
__global__ void k_naive(const float* __restrict__ x, const int* __restrict__ wq,
                        const int* __restrict__ bq, const float* __restrict__ scal,
                        float* __restrict__ out) {
  const int o = blockIdx.x * blockDim.x + threadIdx.x;
  const int b = blockIdx.y;
  const float* xr = x + (size_t)b * IN_F;
  const int* wr = wq + (size_t)o * IN_F;
  float s = 0.f, sx = 0.f;
  for (int k = 0; k < IN_F; ++k) {
    float xv = xr[k];
    s += xv * (float)wr[k];
    sx += xv;
  }
  out[(size_t)b * OUT_F + o] =
      scal[0] * s + scal[1] * sx + scal[2] * (float)bq[o] + scal[3];
}

extern "C" void kernel_launch(void* const* d_in, const int* in_sizes, int n_in,
                              void* d_out, int out_size, void* d_ws, size_t ws_size,
                              hipStream_t stream) {
  const float* x = (const float*)d_in[0];
  const int* wq = (const int*)d_in[1];
  const int* bq = (const int*)d_in[2];
  const float* wmn = (const float*)d_in[3];
  const float* wmx = (const float*)d_in[4];
  const float* bmn = (const float*)d_in[5];
  const float* bmx = (const float*)d_in[6];
  float* out = (float*)d_out;

  char* ws = (char*)d_ws;
  float* scal = (float*)ws;                                  // 16 B (fallback path)
  int* pmin = (int*)(ws + 64);                               // 4 KB
  int* pmax = (int*)(ws + 64 + NPART * 4);                   // 4 KB
  const size_t needed = 64 + 2 * NPART * 4;

  if (ws_size >= needed) {
    k_wmm<<<NPART, 256, 0, stream>>>(wq, pmin, pmax);
    dim3 grid(BATCH / 256, OUT_F / 256);
    k_gemm<<<grid, 512, 0, stream>>>(x, wq, bq, pmin, pmax,
                                     wmn, wmx, bmn, bmx, out);
  } else {
    k_wmm<<<NPART, 256, 0, stream>>>(wq, pmin, pmax);
    k_scal<<<1, 256, 0, stream>>>(pmin, pmax, NPART, bq, wmn, wmx, bmn, bmx, scal);
    k_naive<<<dim3(OUT_F / 256, BATCH), 256, 0, stream>>>(x, wq, bq, scal, out);
  }
}